// Round 1
// baseline (7325.079 us; speedup 1.0000x reference)
//
#include <hip/hip_runtime.h>
#include <math.h>

// TransformerCell: sequential 255-step recurrence.
// Incremental formulation: cache c_i = W2 z_i, V_i = W3 z_i per appended row;
// logit_i = c_i . (W1^T z_prev) / 32. Zero rows contribute (257-t)*exp(-m) to
// the softmax denominator only.
//
// Persistent kernel, grid 256x256, custom 2-level atomic grid barrier.
// Rule: d_in (weights) -> normal cached loads (stay L2-resident, never
// invalidated). ws/d_out (cross-block data) -> relaxed agent-scope atomics
// (sc0/sc1 cache-bypass, coherent at LLC). No acquire/release fences anywhere
// => no buffer_inv => weights stay hot in per-XCD L2.

#define NBLK 256
#define NTHR 256

// ws float offsets (ints bar[] live in first 1024B)
#define OFF_W1T 256         // [512][1024] W1^T
#define OFF_C   524544      // [257][512] c cache
#define OFF_V   656128      // [257][512] V cache
#define OFF_Q   787712      // [512] q
#define OFF_G   788224      // [512] g
#define OFF_LOG 788736      // [257] logits
#define OFF_F1  789248      // [1024]
#define OFF_F2  790272      // [1024]
#define OFF_F3  791296      // [1024]

__device__ __forceinline__ float aload(const float* p) {
  return __hip_atomic_load((float*)p, __ATOMIC_RELAXED, __HIP_MEMORY_SCOPE_AGENT);
}
__device__ __forceinline__ void astore(float* p, float v) {
  __hip_atomic_store(p, v, __ATOMIC_RELAXED, __HIP_MEMORY_SCOPE_AGENT);
}
__device__ __forceinline__ float2 aload2(const float* p) {
  double d = __hip_atomic_load((double*)p, __ATOMIC_RELAXED, __HIP_MEMORY_SCOPE_AGENT);
  return __builtin_bit_cast(float2, d);
}
__device__ __forceinline__ void astore2(float* p, float2 v) {
  __hip_atomic_store((double*)p, __builtin_bit_cast(double, v), __ATOMIC_RELAXED, __HIP_MEMORY_SCOPE_AGENT);
}

__device__ __forceinline__ float wave_reduce(float v) {
#pragma unroll
  for (int off = 1; off < 64; off <<= 1) v += __shfl_xor(v, off, 64);
  return v;
}

// 2-level monotonic barrier: 8 group counters (own cachelines), 1 global, 1 phase.
// All relaxed: prior sc1 stores are LLC-visible before arrival because each
// wave drains vmcnt (s_waitcnt 0) before s_barrier, and the arriving RMW
// issues only after s_barrier completes.
__device__ __forceinline__ void gbar(int* bar, int k, int bid) {
  __atomic_signal_fence(__ATOMIC_SEQ_CST);
  __builtin_amdgcn_s_waitcnt(0);
  __syncthreads();
  if (threadIdx.x == 0) {
    int g = bid & 7;
    int v = __hip_atomic_fetch_add(&bar[g * 16], 1, __ATOMIC_RELAXED, __HIP_MEMORY_SCOPE_AGENT);
    if (v == k * 32 + 31) {
      int w = __hip_atomic_fetch_add(&bar[128], 1, __ATOMIC_RELAXED, __HIP_MEMORY_SCOPE_AGENT);
      if (w == k * 8 + 7)
        __hip_atomic_store(&bar[144], k + 1, __ATOMIC_RELAXED, __HIP_MEMORY_SCOPE_AGENT);
    }
    while (__hip_atomic_load(&bar[144], __ATOMIC_RELAXED, __HIP_MEMORY_SCOPE_AGENT) < k + 1)
      __builtin_amdgcn_s_sleep(1);
  }
  __syncthreads();
  __atomic_signal_fence(__ATOMIC_SEQ_CST);
}

// R=1024 rows, 4/block (one per wave). W/bias: cached loads. x/resid/out: atomics.
template<int K, int MODE>  // MODE 0=linear, 1=leaky_relu(0.01)
__device__ __forceinline__ void mv4(const float* __restrict__ W, const float* __restrict__ x,
                                    const float* __restrict__ bias, const float* resid, float* out,
                                    int bid, int wave, int lane) {
  constexpr int NP = K / 128;
  float2 xr[NP];
#pragma unroll
  for (int i = 0; i < NP; ++i) xr[i] = aload2(x + lane * 2 + 128 * i);
  int r = bid * 4 + wave;
  const float* w = W + (size_t)r * K;
  float acc = 0.f;
#pragma unroll
  for (int i = 0; i < NP; ++i) {
    float2 wf = *(const float2*)(w + lane * 2 + 128 * i);
    acc = fmaf(wf.x, xr[i].x, acc);
    acc = fmaf(wf.y, xr[i].y, acc);
  }
  acc = wave_reduce(acc);
  if (lane == 0) {
    if (bias)  acc += bias[r];
    if (resid) acc += aload(resid + r);
    if (MODE == 1) acc = acc > 0.f ? acc : 0.01f * acc;
    astore(out + r, acc);
  }
}

__global__ void __launch_bounds__(NTHR) tcell(
    const float* __restrict__ mu, const float* __restrict__ z0,
    const float* __restrict__ W1, const float* __restrict__ W2, const float* __restrict__ W3,
    const float* __restrict__ p_in_w, const float* __restrict__ p_in_b,
    const float* __restrict__ p_h0_w, const float* __restrict__ p_h0_b,
    const float* __restrict__ p_h1_w, const float* __restrict__ p_h1_b,
    const float* __restrict__ p_out_w, const float* __restrict__ p_out_b,
    const float* __restrict__ m_in_w, const float* __restrict__ m_in_b,
    const float* __restrict__ m_h0_w, const float* __restrict__ m_h0_b,
    const float* __restrict__ m_h1_w, const float* __restrict__ m_h1_b,
    const float* __restrict__ m_out_w, const float* __restrict__ m_out_b,
    float* __restrict__ Z, float* __restrict__ ws) {
  const int tid = threadIdx.x;
  const int bid = blockIdx.x;
  const int lane = tid & 63;
  const int wave = tid >> 6;

  int* bar = (int*)ws;
  float* W1T = ws + OFF_W1T;
  float* cC  = ws + OFF_C;
  float* vC  = ws + OFF_V;
  float* qv  = ws + OFF_Q;
  float* gv  = ws + OFF_G;
  float* lg  = ws + OFF_LOG;
  float* f1  = ws + OFF_F1;
  float* f2  = ws + OFF_F2;
  float* f3  = ws + OFF_F3;

  __shared__ float sA[256], sB[256], sC[256];
  __shared__ float tile[4][512];

  int bk = 0;

  // ---- P0: W1T[r][j] = W1[j][r]  (once per launch; consumed after barriers)
  {
    int j0 = bid * 4;
    for (int idx = tid; idx < 2048; idx += 256) {
      int jj = idx >> 9, r = idx & 511;
      tile[jj][r] = W1[(size_t)(j0 + jj) * 512 + r];
    }
    __syncthreads();
    for (int r = tid; r < 512; r += 256) {
      astore2(W1T + (size_t)r * 1024 + j0,     make_float2(tile[0][r], tile[1][r]));
      astore2(W1T + (size_t)r * 1024 + j0 + 2, make_float2(tile[2][r], tile[3][r]));
    }
    __syncthreads();
  }

  // ---- MLP_p: z_minus = Z[0]
  {  // P1: f1 = lrelu(p_in_w @ mu + b), K=64
    int r = bid * 4 + wave;
    float acc = p_in_w[(size_t)r * 64 + lane] * mu[lane];
    acc = wave_reduce(acc);
    if (lane == 0) { acc += p_in_b[r]; acc = acc > 0.f ? acc : 0.01f * acc; astore(f1 + r, acc); }
  }
  gbar(bar, bk++, bid);
  mv4<1024, 1>(p_h0_w, f1, p_h0_b, nullptr, f2, bid, wave, lane);
  gbar(bar, bk++, bid);
  mv4<1024, 1>(p_h1_w, f2, p_h1_b, nullptr, f3, bid, wave, lane);
  gbar(bar, bk++, bid);
  mv4<1024, 0>(p_out_w, f3, p_out_b, nullptr, Z, bid, wave, lane);  // Z[0] = z_minus
  if (bid < 4) { int i = bid * 256 + tid; astore(Z + 1024 + i, z0[i]); }  // Z[1] = z_0
  gbar(bar, bk++, bid);

  // ---- P5: c[0] = W2 @ z_minus, V[0] = W3 @ z_minus  (1024 rows, 4/block)
  {
    float2 xr[8];
#pragma unroll
    for (int i = 0; i < 8; ++i) xr[i] = aload2(Z + lane * 2 + 128 * i);
    int r = bid * 4 + wave;
    const float* w = (r < 512) ? (W2 + (size_t)r * 1024) : (W3 + (size_t)(r - 512) * 1024);
    float* dst = (r < 512) ? (cC + r) : (vC + (r - 512));
    float acc = 0.f;
#pragma unroll
    for (int i = 0; i < 8; ++i) {
      float2 wf = *(const float2*)(w + lane * 2 + 128 * i);
      acc = fmaf(wf.x, xr[i].x, acc);
      acc = fmaf(wf.y, xr[i].y, acc);
    }
    acc = wave_reduce(acc);
    if (lane == 0) astore(dst, acc);
  }
  gbar(bar, bk++, bid);

  // ---- main recurrence
  for (int t = 2; t <= 256; ++t) {
    const float* zprev = Z + (size_t)(t - 1) * 1024;

    // A: q = W1^T z_prev; c[t-1] = W2 z_prev; V[t-1] = W3 z_prev  (1536 rows, 6/block)
    {
      float2 xr[8];
#pragma unroll
      for (int i = 0; i < 8; ++i) xr[i] = aload2(zprev + lane * 2 + 128 * i);
      for (int rr = wave; rr < 6; rr += 4) {
        int r = bid * 6 + rr;
        float acc = 0.f;
        if (r < 512) {                       // q rows: W1T lives in ws -> atomic reads
          const float* w = W1T + (size_t)r * 1024;
#pragma unroll
          for (int i = 0; i < 8; ++i) {
            float2 wf = aload2(w + lane * 2 + 128 * i);
            acc = fmaf(wf.x, xr[i].x, acc);
            acc = fmaf(wf.y, xr[i].y, acc);
          }
          acc = wave_reduce(acc);
          if (lane == 0) astore(qv + r, acc);
        } else {
          const float* w = (r < 1024) ? (W2 + (size_t)(r - 512) * 1024)
                                      : (W3 + (size_t)(r - 1024) * 1024);
          float* dst = (r < 1024) ? (cC + (size_t)(t - 1) * 512 + (r - 512))
                                  : (vC + (size_t)(t - 1) * 512 + (r - 1024));
#pragma unroll
          for (int i = 0; i < 8; ++i) {
            float2 wf = *(const float2*)(w + lane * 2 + 128 * i);
            acc = fmaf(wf.x, xr[i].x, acc);
            acc = fmaf(wf.y, xr[i].y, acc);
          }
          acc = wave_reduce(acc);
          if (lane == 0) astore(dst, acc);
        }
      }
    }
    gbar(bar, bk++, bid);

    // B1: logits[i] = c_i . q / 32, block i handles row i
    if (bid < t && wave == 0) {
      const float* crow = cC + (size_t)bid * 512;
      float acc = 0.f;
#pragma unroll
      for (int i = 0; i < 4; ++i) {
        float2 cf = aload2(crow + lane * 2 + 128 * i);
        float2 qf = aload2(qv + lane * 2 + 128 * i);
        acc = fmaf(cf.x, qf.x, acc);
        acc = fmaf(cf.y, qf.y, acc);
      }
      acc = wave_reduce(acc);
      if (lane == 0) astore(lg + bid, acc * 0.03125f);
    }
    gbar(bar, bk++, bid);

    // B2: softmax (incl. 257-t zero rows) + g components 2b, 2b+1
    {
      float l = (tid < t) ? aload(lg + tid) : -1e30f;
      sA[tid] = l; __syncthreads();
      for (int s = 128; s > 0; s >>= 1) { if (tid < s) sA[tid] = fmaxf(sA[tid], sA[tid + s]); __syncthreads(); }
      float m = fmaxf(sA[0], 0.f);
      __syncthreads();
      float e = (tid < t) ? expf(l - m) : 0.f;
      int c0 = bid * 2;
      float p0 = 0.f, p1 = 0.f;
      if (tid < t) {
        p0 = e * aload(vC + (size_t)tid * 512 + c0);
        p1 = e * aload(vC + (size_t)tid * 512 + c0 + 1);
      }
      sA[tid] = e; sB[tid] = p0; sC[tid] = p1; __syncthreads();
      for (int s = 128; s > 0; s >>= 1) {
        if (tid < s) { sA[tid] += sA[tid + s]; sB[tid] += sB[tid + s]; sC[tid] += sC[tid + s]; }
        __syncthreads();
      }
      if (tid == 0) {
        float stot = sA[0] + (float)(257 - t) * expf(-m);
        astore(gv + c0, sB[0] / stot);
        astore(gv + c0 + 1, sC[0] / stot);
      }
    }
    gbar(bar, bk++, bid);

    // MLP_m + residual
    mv4<512, 1>(m_in_w, gv, m_in_b, nullptr, f1, bid, wave, lane);
    gbar(bar, bk++, bid);
    mv4<1024, 1>(m_h0_w, f1, m_h0_b, nullptr, f2, bid, wave, lane);
    gbar(bar, bk++, bid);
    mv4<1024, 1>(m_h1_w, f2, m_h1_b, nullptr, f3, bid, wave, lane);
    gbar(bar, bk++, bid);
    mv4<1024, 0>(m_out_w, f3, m_out_b, zprev, Z + (size_t)t * 1024, bid, wave, lane);
    gbar(bar, bk++, bid);
  }
}

extern "C" void kernel_launch(void* const* d_in, const int* in_sizes, int n_in,
                              void* d_out, int out_size, void* d_ws, size_t ws_size,
                              hipStream_t stream) {
  (void)in_sizes; (void)n_in; (void)out_size; (void)ws_size;
  hipMemsetAsync(d_ws, 0, 1024, stream);  // barrier counters
  tcell<<<dim3(NBLK), dim3(NTHR), 0, stream>>>(
      (const float*)d_in[0],  (const float*)d_in[1],
      (const float*)d_in[2],  (const float*)d_in[3],  (const float*)d_in[4],
      (const float*)d_in[5],  (const float*)d_in[6],
      (const float*)d_in[7],  (const float*)d_in[8],
      (const float*)d_in[9],  (const float*)d_in[10],
      (const float*)d_in[11], (const float*)d_in[12],
      (const float*)d_in[13], (const float*)d_in[14],
      (const float*)d_in[15], (const float*)d_in[16],
      (const float*)d_in[17], (const float*)d_in[18],
      (const float*)d_in[19], (const float*)d_in[20],
      (float*)d_out, (float*)d_ws);
}